// Round 1
// baseline (73.058 us; speedup 1.0000x reference)
//
#include <hip/hip_runtime.h>
#include <math.h>

#define N_POINTS   262144
#define NUM_FREQS  10
#define NUM_VOXELS 512

// W is (1536,63) row-major fp32; voxel v uses rows 3v..3v+2 (189 floats).
// Packed into ws as fp16: Wp[v] = 3 rows x 64 halfs = 384 B, 64B-aligned.
// Layout v2: packed col 0..2 = W col 0..2, col 3 = ZERO PAD, col 4+k = W col
// 3+k. Pad moved from col 63 to col 3 so every half2 pair boundary is even:
// enc pairs are (x0,x1),(x2,0),(s0,s1),(s2,c0),(c1,c2) per freq -> 32 total
// v_cvt_pkrtz_f16_f32 instead of 64 scalar half inserts.
//
// R10 = R9 skeleton with:
//   - 512-thread blocks x 512 grid -> 2 blocks/CU so barrier stalls overlap
//     (R9's 1024x256 = 1 block/CU serialized 7 full-CU barriers)
//   - one barrier removed (redundant per-wave level-2 scan of 8 wave sums)
//   - pkrtz enc packing + matching Wp column remap
//   - pack_w vectorized: 4 halfs/thread, 8B stores

typedef _Float16 half2v __attribute__((ext_vector_type(2)));

__device__ __forceinline__ half2v u2h(unsigned int u) {
    union { unsigned int u; half2v h; } c; c.u = u; return c.h;
}

__device__ __forceinline__ float dot2acc(half2v a, half2v b, float acc) {
#if __has_builtin(__builtin_amdgcn_fdot2)
    return __builtin_amdgcn_fdot2(a, b, acc, false);
#else
    return acc + (float)a[0] * (float)b[0] + (float)a[1] * (float)b[1];
#endif
}

__device__ __forceinline__ half2v pkrtz(float a, float b) {
#if __has_builtin(__builtin_amdgcn_cvt_pkrtz)
    auto r = __builtin_amdgcn_cvt_pkrtz(a, b);   // v_cvt_pkrtz_f16_f32
    union { decltype(r) r_; half2v h; } c; c.r_ = r; return c.h;
#else
    half2v h; h[0] = (_Float16)a; h[1] = (_Float16)b; return h;
#endif
}

// ---------------------------------------------------------------------------
// Pass 1: pack W (fp32 1536x63) -> Wp (fp16 512 x 3 x 64, layout v2).
// 4 halfs per thread, 8B stores.  24576 threads = 96 blocks x 256.
// Runs every call (ws is re-poisoned before every timed launch).
// ---------------------------------------------------------------------------
__global__ __launch_bounds__(256) void pack_w(
    const float* __restrict__ W, _Float16* __restrict__ Wp)
{
    const int gid = blockIdx.x * 256 + threadIdx.x;   // [0, 24576)
    const int v   = gid / 48;                         // voxel
    const int e4  = gid % 48;                         // 4-half group in voxel
    const int row = e4 >> 4;                          // 0..2
    const int g   = e4 & 15;                          // group in row
    union { _Float16 h[4]; float2 f2; } u;
    #pragma unroll
    for (int j = 0; j < 4; ++j) {
        const int pc = 4 * g + j;                     // packed col 0..63
        float val = 0.0f;
        if (pc != 3) {
            const int wc = pc - (pc >= 4);            // W col 0..62
            val = W[v * 189 + row * 63 + wc];
        }
        u.h[j] = (_Float16)val;                       // RNE for weights
    }
    *reinterpret_cast<float2*>(Wp + (size_t)v * 192 + row * 64 + 4 * g) = u.f2;
}

// posenc (double-angle recurrence; 2^f*x exact in fp32, recurrence err ~1e-4)
// packed to half2 via v_cvt_pkrtz, + dot against 3 fp16 rows of voxel v
// (24 uint4 loads over exactly 6 lines).
__device__ __forceinline__ void posenc_pack_dot(
    float x0, float x1, float x2, const _Float16* __restrict__ Wp, int v,
    float& a0, float& a1, float& a2)
{
    half2v eh[32];                       // 64 halfs = 32 VGPRs
    eh[0] = pkrtz(x0, x1);
    eh[1] = pkrtz(x2, 0.0f);             // pairs with zero pad col 3

    float s0, c0, s1, c1, s2, c2;
    __sincosf(x0, &s0, &c0);
    __sincosf(x1, &s1, &c1);
    __sincosf(x2, &s2, &c2);
    #pragma unroll
    for (int f = 0; f < NUM_FREQS; ++f) {
        const int b = 2 + 3 * f;         // pair index of [s0 s1 | s2 c0 | c1 c2]
        eh[b + 0] = pkrtz(s0, s1);
        eh[b + 1] = pkrtz(s2, c0);
        eh[b + 2] = pkrtz(c1, c2);
        if (f < NUM_FREQS - 1) {
            const float ns0 = 2.0f*s0*c0, nc0 = c0*c0 - s0*s0;
            const float ns1 = 2.0f*s1*c1, nc1 = c1*c1 - s1*s1;
            const float ns2 = 2.0f*s2*c2, nc2 = c2*c2 - s2*s2;
            s0 = ns0; c0 = nc0; s1 = ns1; c1 = nc1; s2 = ns2; c2 = nc2;
        }
    }

    const uint4* __restrict__ wb = (const uint4*)(Wp + (size_t)v * 192);
    float acc[3];
    #pragma unroll
    for (int r = 0; r < 3; ++r) {
        float a = 0.0f;
        #pragma unroll
        for (int k = 0; k < 8; ++k) {
            const uint4 q = wb[r * 8 + k];
            a = dot2acc(u2h(q.x), eh[4*k + 0], a);
            a = dot2acc(u2h(q.y), eh[4*k + 1], a);
            a = dot2acc(u2h(q.z), eh[4*k + 2], a);
            a = dot2acc(u2h(q.w), eh[4*k + 3], a);
        }
        acc[r] = a;
    }
    a0 = acc[0]; a1 = acc[1]; a2 = acc[2];
}

// ---------------------------------------------------------------------------
// Pass 2: fused sort + compute + unpermute.  Grid = 512 x 512 = N.
// 2 blocks/CU resident (launch_bounds caps VGPR at 128, LDS ~12.3 KB) so
// barrier stalls of one block overlap with compute of its CU-mate.
// ---------------------------------------------------------------------------
__global__ __launch_bounds__(512, 4) void voxlin_fused(
    const float* __restrict__ X,
    const _Float16* __restrict__ Wp,
    const int* __restrict__ row_ids,
    const int* __restrict__ voxel_ids,
    float* __restrict__ out)
{
    __shared__ float4 pts[512];          // 8 KB: (x,y,z,v) then (a0,a1,a2,-)
    __shared__ int    hist[NUM_VOXELS];
    __shared__ int    cur[NUM_VOXELS];
    __shared__ int    wsum[8];

    const int t    = threadIdx.x;        // [0, 512) -- one thread per bin too
    const int lane = t & 63;
    const int wid  = t >> 6;             // 0..7
    const int i    = blockIdx.x * 512 + t;

    const int   v  = voxel_ids[i];
    const float x0 = X[3*i + 0];
    const float x1 = X[3*i + 1];
    const float x2 = X[3*i + 2];
    const int   r  = row_ids[i];         // stays in this thread's registers

    hist[t] = 0;
    __syncthreads();                                         // B1
    atomicAdd(&hist[v], 1);
    __syncthreads();                                         // B2

    // two-level exclusive scan over 512 bins; every thread owns one bin
    const int c = hist[t];
    int incl = c;
    #pragma unroll
    for (int d = 1; d < 64; d <<= 1) {
        int n = __shfl_up(incl, d);
        if (lane >= d) incl += n;
    }
    if (lane == 63) wsum[wid] = incl;                        // wave totals
    __syncthreads();                                         // B3

    // level 2: every wave redundantly scans the 8 wave totals (no barrier)
    int s8 = (lane < 8) ? wsum[lane] : 0;
    #pragma unroll
    for (int d = 1; d < 8; d <<= 1) {
        int n = __shfl_up(s8, d);
        if (lane >= d) s8 += n;
    }
    int ce = __shfl(s8, (wid == 0) ? 0 : (wid - 1));         // chunk offset
    if (wid == 0) ce = 0;

    cur[t] = ce + incl - c;              // exclusive prefix for bin t
    __syncthreads();                                         // B4

    const int mypos = atomicAdd(&cur[v], 1);     // own point's sorted slot
    pts[mypos] = make_float4(x0, x1, x2, __int_as_float(v));
    __syncthreads();                                         // B5

    // compute for the point sitting at slot t
    const float4 q  = pts[t];
    const int    sv = __float_as_int(q.w);
    float a0, a1, a2;
    posenc_pack_dot(q.x, q.y, q.z, Wp, sv, a0, a1, a2);

    pts[t] = make_float4(a0, a1, a2, 0.0f);      // same slot we read: no race
    __syncthreads();                                         // B6

    // unpermute: fetch own point's result, write in original (coalesced) order
    const float4 res = pts[mypos];
    out[3*r + 0] = res.x;
    out[3*r + 1] = res.y;
    out[3*r + 2] = res.z;
}

// ---------------------------------------------------------------------------
// Fallback (R1 kernel) if ws too small for the 192 KB packed table.
// ---------------------------------------------------------------------------
__global__ __launch_bounds__(256) void voxlin_fallback(
    const float* __restrict__ X, const float* __restrict__ W,
    const int* __restrict__ row_ids, const int* __restrict__ voxel_ids,
    float* __restrict__ out)
{
    const int i = blockIdx.x * 256 + threadIdx.x;
    if (i >= N_POINTS) return;
    const float x0 = X[3*i], x1 = X[3*i+1], x2 = X[3*i+2];
    const int v = voxel_ids[i];
    const float* __restrict__ w0 = W + v * 189;
    const float* __restrict__ w1 = w0 + 63;
    const float* __restrict__ w2 = w0 + 126;
    float a0 = x0*w0[0] + x1*w0[1] + x2*w0[2];
    float a1 = x0*w1[0] + x1*w1[1] + x2*w1[2];
    float a2 = x0*w2[0] + x1*w2[1] + x2*w2[2];
    float s0, c0, s1, c1, s2, c2;
    __sincosf(x0, &s0, &c0); __sincosf(x1, &s1, &c1); __sincosf(x2, &s2, &c2);
    #pragma unroll
    for (int f = 0; f < NUM_FREQS; ++f) {
        const int b = 3 + 6*f;
        a0 += s0*w0[b] + s1*w0[b+1] + s2*w0[b+2] + c0*w0[b+3] + c1*w0[b+4] + c2*w0[b+5];
        a1 += s0*w1[b] + s1*w1[b+1] + s2*w1[b+2] + c0*w1[b+3] + c1*w1[b+4] + c2*w1[b+5];
        a2 += s0*w2[b] + s1*w2[b+1] + s2*w2[b+2] + c0*w2[b+3] + c1*w2[b+4] + c2*w2[b+5];
        if (f < NUM_FREQS - 1) {
            const float ns0 = 2.0f*s0*c0, nc0 = c0*c0 - s0*s0;
            const float ns1 = 2.0f*s1*c1, nc1 = c1*c1 - s1*s1;
            const float ns2 = 2.0f*s2*c2, nc2 = c2*c2 - s2*s2;
            s0 = ns0; c0 = nc0; s1 = ns1; c1 = nc1; s2 = ns2; c2 = nc2;
        }
    }
    const int rr = row_ids[i];
    out[3*rr] = a0; out[3*rr+1] = a1; out[3*rr+2] = a2;
}

// ---------------------------------------------------------------------------
extern "C" void kernel_launch(void* const* d_in, const int* in_sizes, int n_in,
                              void* d_out, int out_size, void* d_ws, size_t ws_size,
                              hipStream_t stream) {
    const float* X         = (const float*)d_in[0];
    const float* W         = (const float*)d_in[1];
    const int*   row_ids   = (const int*)d_in[2];
    const int*   voxel_ids = (const int*)d_in[3];
    float*       out       = (float*)d_out;

    const size_t need = (size_t)NUM_VOXELS * 192 * sizeof(_Float16); // 192 KB

    if (ws_size >= need) {
        _Float16* Wp = (_Float16*)d_ws;
        pack_w<<<96, 256, 0, stream>>>(W, Wp);
        voxlin_fused<<<512, 512, 0, stream>>>(X, Wp, row_ids, voxel_ids, out);
    } else {
        voxlin_fallback<<<(N_POINTS + 255) / 256, 256, 0, stream>>>(X, W, row_ids, voxel_ids, out);
    }
}